// Round 4
// baseline (257.009 us; speedup 1.0000x reference)
//
#include <hip/hip_runtime.h>
#include <hip/hip_bf16.h>

// ThresholdEncode: x (N floats in [0,1)) -> (N, 64) float32 spike matrix.
// Row j (j < N-1): col 2i   = (x[j] <= th[i]) & (x[j+1] >  th[i])  (up)
//                  col 2i+1 = (x[j] >  th[i]) & (x[j+1] <= th[i])  (down)
// th[i] = float32( (i+1) * (1/33) computed in double )  -- matches np.linspace
// Row N-1: all zeros.
//
// One thread per output float4, exact grid (no loop) — fill-kernel shape
// (fillBufferAligned sustains 6.5 TB/s on this buffer with plain stores).
// NOTE: nontemporal stores LOST WRITES under graph replay (L2-bypass vs
// dirty poison lines in L2) — round 3 post-timing failure. Plain stores only.

typedef float f32x4 __attribute__((ext_vector_type(4)));

__global__ __launch_bounds__(256) void ThresholdEncode_kernel(
    const float* __restrict__ x, f32x4* __restrict__ out, int n) {
    const int idx = blockIdx.x * 256 + threadIdx.x;  // one float4 per thread
    const int total = n * 16;
    if (idx >= total) return;
    const int j = idx >> 4;            // row
    const int c = idx & 15;            // which float4 within the row
    f32x4 v = (f32x4)(0.f, 0.f, 0.f, 0.f);
    if (j < n - 1) {
        const float xp = x[j];
        const float xn = x[j + 1];
        const int i0 = 2 * c;          // threshold indices for this quad
        const int i1 = 2 * c + 1;
        // Exact np.linspace(0,1,34,dtype=f32)[1:-1] semantics:
        // compute in double, round once to float.
        const float t0 = (float)((double)(i0 + 1) * (1.0 / 33.0));
        const float t1 = (float)((double)(i1 + 1) * (1.0 / 33.0));
        v.x = (xp <= t0 && xn >  t0) ? 1.0f : 0.0f;  // up   i0
        v.y = (xp >  t0 && xn <= t0) ? 1.0f : 0.0f;  // down i0
        v.z = (xp <= t1 && xn >  t1) ? 1.0f : 0.0f;  // up   i1
        v.w = (xp >  t1 && xn <= t1) ? 1.0f : 0.0f;  // down i1
    }
    out[idx] = v;
}

extern "C" void kernel_launch(void* const* d_in, const int* in_sizes, int n_in,
                              void* d_out, int out_size, void* d_ws, size_t ws_size,
                              hipStream_t stream) {
    const float* x = (const float*)d_in[0];
    f32x4* out = (f32x4*)d_out;
    const int n = in_sizes[0];             // 1,000,000
    const int total = n * 16;              // float4 count = 16,000,000
    const int block = 256;
    const int grid = (total + block - 1) / block;  // 62,500 blocks
    ThresholdEncode_kernel<<<grid, block, 0, stream>>>(x, out, n);
}

// Round 5
// 244.635 us; speedup vs baseline: 1.0506x; 1.0506x over previous
//
#include <hip/hip_runtime.h>
#include <hip/hip_bf16.h>

// ThresholdEncode: x (N floats in [0,1)) -> (N, 64) float32 spike matrix.
// Row j (j < N-1): col 2i   = (x[j] <= th[i]) & (x[j+1] >  th[i])  (up)
//                  col 2i+1 = (x[j] >  th[i]) & (x[j+1] <= th[i])  (down)
// th[i] = float32( (i+1) * (1/33) computed in double )  -- matches np.linspace
// Row N-1: all zeros.
//
// Round-4 finding: kernel was VMEM *issue-rate* bound (48M wave-VMEM ops,
// ~1.25 cyc/op), not BW bound (2.6 TB/s vs fill's 6.6 TB/s on same buffer).
// Fix: 8 rows x 1 quad per thread -> 3 loads + 8 stores per thread (22M total
// VMEM, stores now the floor). Store coalescing unchanged: per wave-store,
// 4 x 256B segments == 8 x 128B transactions, same as fully contiguous.
// NOTE: nontemporal stores LOST WRITES under graph replay (round 3) — plain
// stores only.

typedef float f32x4 __attribute__((ext_vector_type(4)));

__global__ __launch_bounds__(256) void ThresholdEncode_kernel(
    const float* __restrict__ x, f32x4* __restrict__ out, int n) {
    const int t = blockIdx.x * 256 + threadIdx.x;
    const int ngroups = (n + 7) >> 3;          // groups of 8 rows
    if (t >= ngroups * 16) return;
    const int c  = t & 15;                     // quad (4 cols) within row
    const int g  = t >> 4;                     // row group
    const int j0 = g << 3;                     // first row of group

    // Thresholds for this quad — exact np.linspace(0,1,34,f32)[1:-1]:
    // compute in double, round once to float.
    const float t0 = (float)((double)(2 * c + 1) * (1.0 / 33.0));
    const float t1 = (float)((double)(2 * c + 2) * (1.0 / 33.0));

    // Load x[j0 .. j0+8] : two aligned float4 + one boundary scalar.
    float xv[9];
    if (j0 + 8 <= n) {                         // fast path (always for n%8==0)
        const f32x4 a = *(const f32x4*)(x + j0);
        const f32x4 b = *(const f32x4*)(x + j0 + 4);
        xv[0]=a.x; xv[1]=a.y; xv[2]=a.z; xv[3]=a.w;
        xv[4]=b.x; xv[5]=b.y; xv[6]=b.z; xv[7]=b.w;
        xv[8] = (j0 + 8 < n) ? x[j0 + 8] : 0.0f;
    } else {                                   // generic tail (n % 8 != 0)
        #pragma unroll
        for (int k = 0; k < 9; ++k) xv[k] = (j0 + k < n) ? x[j0 + k] : 0.0f;
    }

    #pragma unroll
    for (int k = 0; k < 8; ++k) {              // static indexing -> registers
        const int j = j0 + k;
        if (j >= n) break;
        f32x4 v = (f32x4)(0.f, 0.f, 0.f, 0.f);
        if (j < n - 1) {
            const float xp = xv[k];
            const float xn = xv[k + 1];
            v.x = (xp <= t0 && xn >  t0) ? 1.0f : 0.0f;  // up   2c
            v.y = (xp >  t0 && xn <= t0) ? 1.0f : 0.0f;  // down 2c
            v.z = (xp <= t1 && xn >  t1) ? 1.0f : 0.0f;  // up   2c+1
            v.w = (xp >  t1 && xn <= t1) ? 1.0f : 0.0f;  // down 2c+1
        }
        out[j * 16 + c] = v;                   // wave-store: 4x256B segments
    }
}

extern "C" void kernel_launch(void* const* d_in, const int* in_sizes, int n_in,
                              void* d_out, int out_size, void* d_ws, size_t ws_size,
                              hipStream_t stream) {
    const float* x = (const float*)d_in[0];
    f32x4* out = (f32x4*)d_out;
    const int n = in_sizes[0];                 // 1,000,000
    const int ngroups = (n + 7) >> 3;          // 125,000
    const int threads = ngroups * 16;          // 2,000,000
    const int block = 256;
    const int grid = (threads + block - 1) / block;  // 7,813 blocks
    ThresholdEncode_kernel<<<grid, block, 0, stream>>>(x, out, n);
}